// Round 17
// baseline (698.820 us; speedup 1.0000x reference)
//
#include <hip/hip_runtime.h>
#include <hip/hip_bf16.h>
#include <math.h>

// All scratch in module-owned device memory (d_ws unused).
// Layout (floats):
#define OFF_U     0        // 4096: U[k][d] = W_eff[k][d] = Q[d][k]
#define OFF_BEFF  4096     // 512: sigmoid(beta)
#define OFF_FEATS 5504     // 256*48 = 12288
#define OFF_DENP  17792    // 1024
#define OFF_NUMP  18816    // 256
#define OFF_SQP   19072    // 256*48 = 12288
#define OFF_V     31360    // 256*8*128 = 262144  [bn][k][t]
#define OFF_Y     293504   // 256*512 = 131072   [bn][d]
#define OFF_YP    424576   // 256*8*512 = 1048576 [bn][slice][d]
#define WS_TOTAL  1473152  // 5.9 MB

__device__ __align__(16) float g_ws[WS_TOTAL];
__device__ int g_bar[8];

static __device__ __forceinline__ float wred64(float v){
  #pragma unroll
  for (int m = 32; m >= 1; m >>= 1) v += __shfl_xor(v, m, 64);
  return v;
}

// reduce-scatter 8 values across 64 lanes; returns slot brv3(l&7)'s full sum.
static __device__ __forceinline__ float rs8(float e[8], int l){
  if (l & 1){ float t;
    t=e[0];e[0]=e[4];e[4]=t; t=e[1];e[1]=e[5];e[5]=t;
    t=e[2];e[2]=e[6];e[6]=t; t=e[3];e[3]=e[7];e[7]=t; }
  e[0]+=__shfl_xor(e[4],1,64); e[1]+=__shfl_xor(e[5],1,64);
  e[2]+=__shfl_xor(e[6],1,64); e[3]+=__shfl_xor(e[7],1,64);
  if (l & 2){ float t;
    t=e[0];e[0]=e[2];e[2]=t; t=e[1];e[1]=e[3];e[3]=t; }
  e[0]+=__shfl_xor(e[2],2,64); e[1]+=__shfl_xor(e[3],2,64);
  if (l & 4){ float t=e[0];e[0]=e[1];e[1]=t; }
  e[0]+=__shfl_xor(e[1],4,64);
  e[0]+=__shfl_xor(e[0],8,64);
  e[0]+=__shfl_xor(e[0],16,64);
  e[0]+=__shfl_xor(e[0],32,64);
  return e[0];
}
#define BRV3(c) ((((c)&1)<<2)|((c)&2)|(((c)&4)>>2))

// device-wide spin barrier: all 1024 blocks co-resident (launch_bounds(256,4)).
static __device__ __forceinline__ void gridbar(int ph){
  __syncthreads();
  if (threadIdx.x == 0){
    __threadfence();                       // release prior writes (device scope)
    atomicAdd(&g_bar[ph], 1);
    while (__hip_atomic_load(&g_bar[ph], __ATOMIC_ACQUIRE,
                             __HIP_MEMORY_SCOPE_AGENT) < 1024){
      __builtin_amdgcn_s_sleep(8);
    }
    __threadfence();                       // acquire others' writes
  }
  __syncthreads();
}

// ---------------- K1: QR of W_proj^T (512x8) + sigmoid(beta) + barrier reset --------
__global__ __launch_bounds__(64) void k1_prep(const float* __restrict__ Wp,
                                              const float* __restrict__ beta){
  int l = threadIdx.x;
  if (l < 8) g_bar[l] = 0;
  #pragma unroll
  for (int i = 0; i < 8; i++){
    int d = i*64 + l;
    g_ws[OFF_BEFF + d] = 1.0f/(1.0f + expf(-beta[d]));
  }
  float A[8][8], Q[8][8], tau[8];
  #pragma unroll
  for (int c = 0; c < 8; c++)
    #pragma unroll
    for (int p = 0; p < 8; p++)
      A[c][p] = Wp[c*512 + p*64 + l];   // row d = p*64+l
  #pragma unroll
  for (int j = 0; j < 8; j++){
    float alpha = __shfl(A[j][0], j, 64);
    float ssq = 0.0f;
    #pragma unroll
    for (int p = 0; p < 8; p++){
      bool live = (p > 0) || (l > j);
      float v = A[j][p];
      ssq += live ? v*v : 0.0f;
    }
    ssq = wred64(ssq);
    float tj, scale;
    if (ssq == 0.0f){ tj = 0.0f; scale = 0.0f; }
    else {
      float bta = -copysignf(sqrtf(alpha*alpha + ssq), alpha);
      tj = (bta - alpha)/bta;
      scale = 1.0f/(alpha - bta);
    }
    tau[j] = tj;
    #pragma unroll
    for (int p = 0; p < 8; p++){
      int row = p*64 + l;
      float v = A[j][p]*scale;
      A[j][p] = (row < j) ? 0.0f : (row == j ? 1.0f : v);
    }
    float e[8];
    #pragma unroll
    for (int c = 0; c < 8; c++){
      float d = 0.0f;
      #pragma unroll
      for (int p = 0; p < 8; p++) d += A[c][p]*A[j][p];
      e[c] = (c > j) ? d : 0.0f;
    }
    float s = rs8(e, l);
    #pragma unroll
    for (int c = j+1; c < 8; c++){
      float d = __shfl(s, BRV3(c), 64)*tj;
      #pragma unroll
      for (int p = 0; p < 8; p++) A[c][p] -= d*A[j][p];
    }
  }
  #pragma unroll
  for (int c = 0; c < 8; c++)
    #pragma unroll
    for (int p = 0; p < 8; p++)
      Q[c][p] = (p == 0 && l == c) ? 1.0f : 0.0f;
  #pragma unroll
  for (int j = 7; j >= 0; j--){
    float e[8];
    #pragma unroll
    for (int c = 0; c < 8; c++){
      float d = 0.0f;
      #pragma unroll
      for (int p = 0; p < 8; p++) d += Q[c][p]*A[j][p];
      e[c] = d;
    }
    float s = rs8(e, l);
    #pragma unroll
    for (int c = 0; c < 8; c++){
      float d = __shfl(s, BRV3(c), 64)*tau[j];
      #pragma unroll
      for (int p = 0; p < 8; p++) Q[c][p] -= d*A[j][p];
    }
  }
  #pragma unroll
  for (int c = 0; c < 8; c++)
    #pragma unroll
    for (int p = 0; p < 8; p++)
      g_ws[OFF_U + c*512 + p*64 + l] = Q[c][p];   // U[c][d] = Q[d][c]
}

// ---------------- MEGA: P1 k2 | P2 k3 | P3 k4a | P4 k4b | P5 k7 ---------------------
__global__ __launch_bounds__(256, 4) void mega(const float* __restrict__ x,
                                               const float* __restrict__ vmask,
                                               const float* __restrict__ W1,
                                               const float* __restrict__ b1,
                                               const float* __restrict__ W2,
                                               float* __restrict__ outt){
  int bid = blockIdx.x;
  int tid = threadIdx.x;
  int l = tid & 63, wv = tid >> 6;

  // ================= P1: projection (k2 body, 1024 blocks) ==========================
  {
    __shared__ float denw[4];
    int g = bid*4 + wv;
    float u[8][8];
    #pragma unroll
    for (int k = 0; k < 8; k++){
      #pragma unroll
      for (int e = 0; e < 4; e++) u[k][e]   = g_ws[OFF_U + k*512 + l*4 + e];
      #pragma unroll
      for (int e = 0; e < 4; e++) u[k][4+e] = g_ws[OFF_U + k*512 + 256 + l*4 + e];
    }
    int kk = BRV3(l & 7);
    float pacc[8], psq[8];
    #pragma unroll
    for (int rr = 0; rr < 8; rr++){
      int row = g*8 + rr;
      const float* xr = x + (size_t)row*512;
      float4 xa = *(const float4*)(xr + l*4);
      float4 xb = *(const float4*)(xr + 256 + l*4);
      float xe[8] = {xa.x, xa.y, xa.z, xa.w, xb.x, xb.y, xb.z, xb.w};
      float acc[8];
      float sq = 0.0f;
      #pragma unroll
      for (int k = 0; k < 8; k++){
        float a = 0.0f;
        #pragma unroll
        for (int e = 0; e < 8; e++) a += xe[e]*u[k][e];
        acc[k] = a;
      }
      #pragma unroll
      for (int e = 0; e < 8; e++) sq += xe[e]*xe[e];
      if (l & 1){ float t;
        t=acc[0];acc[0]=acc[4];acc[4]=t; t=acc[1];acc[1]=acc[5];acc[5]=t;
        t=acc[2];acc[2]=acc[6];acc[6]=t; t=acc[3];acc[3]=acc[7];acc[7]=t; }
      acc[0] += __shfl_xor(acc[4], 1, 64);
      acc[1] += __shfl_xor(acc[5], 1, 64);
      acc[2] += __shfl_xor(acc[6], 1, 64);
      acc[3] += __shfl_xor(acc[7], 1, 64);
      if (l & 2){ float t;
        t=acc[0];acc[0]=acc[2];acc[2]=t; t=acc[1];acc[1]=acc[3];acc[3]=t; }
      acc[0] += __shfl_xor(acc[2], 2, 64);
      acc[1] += __shfl_xor(acc[3], 2, 64);
      if (l & 4){ float t=acc[0];acc[0]=acc[1];acc[1]=t; }
      acc[0] += __shfl_xor(acc[1], 4, 64);
      pacc[rr] = acc[0];
      psq[rr]  = sq;
    }
    #pragma unroll
    for (int rr = 0; rr < 8; rr++){
      pacc[rr] += __shfl_xor(pacc[rr],  8, 64);
      pacc[rr] += __shfl_xor(pacc[rr], 16, 64);
      pacc[rr] += __shfl_xor(pacc[rr], 32, 64);
    }
    float dsq = sqrtf(rs8(psq, l));
    dsq += __shfl_xor(dsq, 1, 64);
    dsq += __shfl_xor(dsq, 2, 64);
    dsq += __shfl_xor(dsq, 4, 64);
    float c0 = (l & 32) ? pacc[4] : pacc[0];
    float c1 = (l & 32) ? pacc[5] : pacc[1];
    float c2 = (l & 32) ? pacc[6] : pacc[2];
    float c3 = (l & 32) ? pacc[7] : pacc[3];
    float d0 = (l & 16) ? c2 : c0;
    float d1 = (l & 16) ? c3 : c1;
    float val = (l & 8) ? d1 : d0;
    int rowl = g*8 + (l >> 3);
    float vm = vmask[rowl];
    int b = rowl >> 14, t = (rowl >> 7) & 127, n = rowl & 127;
    int bn = b*128 + n;
    g_ws[OFF_V + bn*1024 + kk*128 + t] = val*vm;
    if (l == 0) denw[wv] = dsq;
    __syncthreads();
    if (tid == 0) g_ws[OFF_DENP + bid] = denw[0]+denw[1]+denw[2]+denw[3];
  }
  gridbar(0);

  // ================= P2: sort + feats (k3 body, blocks < 512) =======================
  if (bid < 512){
    int rho = bid*4 + wv;
    __shared__ float orig[4][128], srt[4][128], Bl[384];
    __shared__ float pS[4][128];
    __shared__ int   pC[4][128];
    __shared__ float nrmS[2];
    if (tid < 128){
      float t = -1.0f + 2.0f*(float)tid/127.0f;
      Bl[128+tid] = t;
      Bl[256+tid] = 0.5f*(3.0f*t*t - 1.0f);
    }
    const float* vr = g_ws + OFF_V + rho*128;
    orig[wv][2*l]   = vr[2*l];
    orig[wv][2*l+1] = vr[2*l+1];
    srt[wv][2*l] = 0.0f; srt[wv][2*l+1] = 0.0f;
    __syncthreads();
    if (tid < 64){
      float a = Bl[128+tid]*Bl[128+tid] + Bl[192+tid]*Bl[192+tid];
      float b = Bl[256+tid]*Bl[256+tid] + Bl[320+tid]*Bl[320+tid];
      a = wred64(a); b = wred64(b);
      if (tid == 0){
        nrmS[0] = sqrtf(fmaxf(a, 1e-6f));
        nrmS[1] = sqrtf(fmaxf(b, 1e-6f));
      }
    }
    __syncthreads();
    if (tid < 128){
      Bl[tid] = 0.08838834764831845f;
      Bl[128+tid] /= nrmS[0];
      Bl[256+tid] /= nrmS[1];
    }
    __syncthreads();
    float c0, c1, c2;
    {
      float a = orig[wv][2*l], b = orig[wv][2*l+1];
      c0 = a*Bl[2*l]       + b*Bl[2*l+1];
      c1 = a*Bl[128+2*l]   + b*Bl[128+2*l+1];
      c2 = a*Bl[256+2*l]   + b*Bl[256+2*l+1];
    }
    c0 = wred64(c0); c1 = wred64(c1); c2 = wred64(c2);
    float e0 = orig[wv][2*l], e1 = orig[wv][2*l+1];
    int r0 = 0, r1 = 0;
    #pragma unroll 4
    for (int j = 0; j < 128; j++){
      float vj = orig[wv][j];
      r0 += (vj < e0) || (vj == e0 && j < 2*l);
      r1 += (vj < e1) || (vj == e1 && j < 2*l+1);
    }
    srt[wv][r0] = e0;
    srt[wv][r1] = e1;
    __syncthreads();
    const float rinv = 22.627416997969522f;
    bool v0 = (srt[wv][2*l+1] - srt[wv][2*l] > rinv);
    bool v1 = (2*l + 2 < 128) ? (srt[wv][2*l+2] - srt[wv][2*l+1] > rinv) : false;
    if (__any(v0 || v1)){
      if (l == 0){
        int top = -1;
        for (int i = 0; i < 128; i++){
          float y = (float)(128 - i)*rinv + srt[wv][i];
          top++; pS[wv][top] = y; pC[wv][top] = 1;
          while (top > 0 &&
                 pS[wv][top]*(float)pC[wv][top-1] > pS[wv][top-1]*(float)pC[wv][top]){
            pS[wv][top-1] += pS[wv][top];
            pC[wv][top-1] += pC[wv][top];
            top--;
          }
        }
        int i = 0;
        for (int blk = 0; blk <= top; blk++){
          float m = pS[wv][blk]/(float)pC[wv][blk];
          for (int c = 0; c < pC[wv][blk]; c++){
            srt[wv][i] = m - (float)(128 - i)*rinv;
            i++;
          }
        }
      }
    }
    if (l == 0){
      int bn = rho >> 3, k = rho & 7;
      float* fb = g_ws + OFF_FEATS + bn*48 + k*6;
      float w0 = 0.1f*127.0f - 12.0f;
      float w1 = 0.5f*127.0f - 63.0f;
      float w2 = 0.9f*127.0f - 114.0f;
      fb[0] = (1.0f - w0)*srt[wv][12]  + w0*srt[wv][13];
      fb[1] = (1.0f - w1)*srt[wv][63]  + w1*srt[wv][64];
      fb[2] = (1.0f - w2)*srt[wv][114] + w2*srt[wv][115];
      fb[3] = c0; fb[4] = c1; fb[5] = c2;
    }
  }
  gridbar(1);

  // ================= P3: head partials (k4a at 256 thr: d = tid, tid+256) ===========
  {
    int s   = bid & 7;
    int bnp = bid >> 3;
    int bn0 = bnp*2, bn1 = bn0 + 1;
    __shared__ float hl0[96], hl1[96];
    __shared__ float sqa[4][12];
    if (tid < 192){
      int which = tid >= 96;
      int i = which ? tid - 96 : tid;
      int f = s*6 + (i >> 4);
      int k = f*16 + (i & 15);
      int bn = which ? bn1 : bn0;
      float a = g_ws[OFF_FEATS + bn*48 + f]*W1[k] + b1[k];
      float g = 0.5f*a*(1.0f + erff(a*0.70710678118654752f));
      if (which) hl1[i] = g; else hl0[i] = g;
    }
    __syncthreads();
    float bea = g_ws[OFF_BEFF + tid];
    float beb = g_ws[OFF_BEFF + tid + 256];
    float b2a = bea*bea, b2b = beb*beb;
    float y0a = 0, y0b = 0, y1a = 0, y1b = 0;
    float ev[12];
    const float* w2a = W2 + (size_t)(s*96)*512 + tid;
    #pragma unroll
    for (int fl_ = 0; fl_ < 6; fl_++){
      float p0a = 0, p0b = 0, p1a = 0, p1b = 0;
      #pragma unroll
      for (int w = 0; w < 16; w++){
        float wa = w2a[(size_t)(fl_*16 + w)*512];
        float wb = w2a[(size_t)(fl_*16 + w)*512 + 256];
        float h0 = hl0[fl_*16 + w], h1 = hl1[fl_*16 + w];
        p0a += h0*wa; p0b += h0*wb;
        p1a += h1*wa; p1b += h1*wb;
      }
      y0a += p0a; y0b += p0b; y1a += p1a; y1b += p1b;
      ev[fl_*2]     = p0a*p0a*b2a + p0b*p0b*b2b;
      ev[fl_*2 + 1] = p1a*p1a*b2a + p1b*p1b*b2b;
    }
    g_ws[OFF_YP + (size_t)(bn0*8 + s)*512 + tid]       = y0a;
    g_ws[OFF_YP + (size_t)(bn0*8 + s)*512 + tid + 256] = y0b;
    g_ws[OFF_YP + (size_t)(bn1*8 + s)*512 + tid]       = y1a;
    g_ws[OFF_YP + (size_t)(bn1*8 + s)*512 + tid + 256] = y1b;
    int kk = BRV3(l & 7);
    {
      float e8[8] = {ev[0],ev[1],ev[2],ev[3],ev[4],ev[5],ev[6],ev[7]};
      float a0 = rs8(e8, l);
      if (l < 8) sqa[wv][kk] = a0;
    }
    {
      float e8[8] = {ev[8],ev[9],ev[10],ev[11],0,0,0,0};
      float a0 = rs8(e8, l);
      if (l < 8 && kk < 4) sqa[wv][8 + kk] = a0;
    }
    __syncthreads();
    if (tid < 12){
      float t = sqa[0][tid] + sqa[1][tid] + sqa[2][tid] + sqa[3][tid];
      int fl_ = tid >> 1, which = tid & 1;
      int bn = which ? bn1 : bn0;
      g_ws[OFF_SQP + bn*48 + s*6 + fl_] = t;
    }
  }
  gridbar(2);

  // ================= P4: y reduce + num (256 thr, blocks < 256) =====================
  if (bid < 256){
    __shared__ float nw[4];
    int bn = bid;
    float ya = 0, yb = 0;
    #pragma unroll
    for (int s = 0; s < 8; s++){
      ya += g_ws[OFF_YP + (size_t)(bn*8 + s)*512 + tid];
      yb += g_ws[OFF_YP + (size_t)(bn*8 + s)*512 + tid + 256];
    }
    g_ws[OFF_Y + bn*512 + tid]       = ya;
    g_ws[OFF_Y + bn*512 + tid + 256] = yb;
    float bea = g_ws[OFF_BEFF + tid];
    float beb = g_ws[OFF_BEFF + tid + 256];
    float bya = bea*ya, byb = beb*yb;
    float ns = wred64(bya*bya + byb*byb);
    if (l == 0) nw[wv] = ns;
    __syncthreads();
    if (tid == 0) g_ws[OFF_NUMP + bn] = sqrtf(nw[0]+nw[1]+nw[2]+nw[3]);
  }
  gridbar(3);

  // ================= P5: h epilogue (grid-stride) + r/r_feat tail in block 0 ========
  for (int q = bid*256 + tid; q < 4194304; q += 262144){
    size_t fl = (size_t)q*4;
    int d = (int)(fl & 511);
    int row = (int)(fl >> 9);
    int b = row >> 14, n = row & 127;
    int bn = b*128 + n;
    float vm = vmask[row];
    float4 xv = *(const float4*)(x + fl);
    float4 yv = *(const float4*)(g_ws + OFF_Y + bn*512 + d);
    float4 bv = *(const float4*)(g_ws + OFF_BEFF + d);
    float4 o;
    o.x = xv.x + vm*bv.x*yv.x;
    o.y = xv.y + vm*bv.y*yv.y;
    o.z = xv.z + vm*bv.z*yv.z;
    o.w = xv.w + vm*bv.w*yv.w;
    *(float4*)(outt + fl) = o;
  }
  if (bid == 0){
    __shared__ float red[256];
    __shared__ float en[96];
    __shared__ float scal[2];
    float dp = 0.0f;
    for (int i = tid; i < 1024; i += 256) dp += g_ws[OFF_DENP + i];
    red[tid] = dp; __syncthreads();
    for (int s = 128; s > 0; s >>= 1){
      if (tid < s) red[tid] += red[tid + s];
      __syncthreads();
    }
    if (tid == 0) scal[0] = fmaxf(red[0]/32768.0f, 1e-9f);
    __syncthreads();
    red[tid] = g_ws[OFF_NUMP + tid];
    __syncthreads();
    for (int s = 128; s > 0; s >>= 1){
      if (tid < s) red[tid] += red[tid + s];
      __syncthreads();
    }
    if (tid == 0) scal[1] = red[0]/256.0f;
    __syncthreads();
    float den = scal[0];
    if (tid < 96){
      int b = tid/48, f = tid%48;
      float s = 0.0f;
      for (int j = 0; j < 128; j++) s += g_ws[OFF_SQP + (b*128 + j)*48 + f];
      en[tid] = sqrtf(128.0f*s);
    }
    __syncthreads();
    if (tid == 0) outt[16777216] = scal[1]/den;
    if (tid < 48) outt[16777217 + tid] = 0.5f*(en[tid] + en[48 + tid])/den;
  }
}

extern "C" void kernel_launch(void* const* d_in, const int* in_sizes, int n_in,
                              void* d_out, int out_size, void* d_ws, size_t ws_size,
                              hipStream_t stream){
  (void)out_size; (void)d_ws; (void)ws_size;
  const float *x=nullptr,*vm=nullptr,*Wp=nullptr,*W1=nullptr,*b1=nullptr,*W2=nullptr,*beta=nullptr;
  for (int i = 0; i < n_in; i++){
    int s = in_sizes[i];
    const float* p = (const float*)d_in[i];
    if      (s == 16777216) x = p;
    else if (s == 32768)    vm = p;
    else if (s == 4096)     Wp = p;
    else if (s == 393216)   W2 = p;
    else if (s == 512)      beta = p;
    else if (s == 768)      { if (!W1) W1 = p; else b1 = p; }
  }
  float* out = (float*)d_out;

  k1_prep<<<1, 64, 0, stream>>>(Wp, beta);
  mega<<<1024, 256, 0, stream>>>(x, vm, W1, b1, W2, out);
}

// Round 18
// 82.430 us; speedup vs baseline: 8.4777x; 8.4777x over previous
//
#include <hip/hip_runtime.h>
#include <hip/hip_bf16.h>
#include <math.h>

// All scratch in module-owned device memory (d_ws unused).
// Layout (floats):
#define OFF_U     0        // 4096: U[k][d] = W_eff[k][d] = Q[d][k]
#define OFF_FEATS 5504     // 256*48 = 12288
#define OFF_DENP  17792    // 1024
#define OFF_NUMP  18816    // 256
#define OFF_SQP   19072    // 256*48 = 12288
#define OFF_V     31360    // 256*8*128 = 262144  [bn][k][t]
#define OFF_Y     293504   // 256*512 = 131072   [bn][d]
#define OFF_YP    424576   // 256*8*512 = 1048576 [bn][slice][d]
#define WS_TOTAL  1473152  // 5.9 MB

__device__ __align__(16) float g_ws[WS_TOTAL];

static __device__ __forceinline__ float wred64(float v){
  #pragma unroll
  for (int m = 32; m >= 1; m >>= 1) v += __shfl_xor(v, m, 64);
  return v;
}

// reduce-scatter 8 values across 64 lanes; returns slot brv3(l&7)'s full sum.
static __device__ __forceinline__ float rs8(float e[8], int l){
  if (l & 1){ float t;
    t=e[0];e[0]=e[4];e[4]=t; t=e[1];e[1]=e[5];e[5]=t;
    t=e[2];e[2]=e[6];e[6]=t; t=e[3];e[3]=e[7];e[7]=t; }
  e[0]+=__shfl_xor(e[4],1,64); e[1]+=__shfl_xor(e[5],1,64);
  e[2]+=__shfl_xor(e[6],1,64); e[3]+=__shfl_xor(e[7],1,64);
  if (l & 2){ float t;
    t=e[0];e[0]=e[2];e[2]=t; t=e[1];e[1]=e[3];e[3]=t; }
  e[0]+=__shfl_xor(e[2],2,64); e[1]+=__shfl_xor(e[3],2,64);
  if (l & 4){ float t=e[0];e[0]=e[1];e[1]=t; }
  e[0]+=__shfl_xor(e[1],4,64);
  e[0]+=__shfl_xor(e[0],8,64);
  e[0]+=__shfl_xor(e[0],16,64);
  e[0]+=__shfl_xor(e[0],32,64);
  return e[0];
}
#define BRV3(c) ((((c)&1)<<2)|((c)&2)|(((c)&4)>>2))

// ---------------- K1: QR of W_proj^T (512x8), LAPACK convention, batched dots -------
__global__ __launch_bounds__(64) void k1_prep(const float* __restrict__ Wp){
  int l = threadIdx.x;
  float A[8][8], Q[8][8], tau[8];
  #pragma unroll
  for (int c = 0; c < 8; c++)
    #pragma unroll
    for (int p = 0; p < 8; p++)
      A[c][p] = Wp[c*512 + p*64 + l];   // row d = p*64+l
  #pragma unroll
  for (int j = 0; j < 8; j++){
    float alpha = __shfl(A[j][0], j, 64);
    float ssq = 0.0f;
    #pragma unroll
    for (int p = 0; p < 8; p++){
      bool live = (p > 0) || (l > j);
      float v = A[j][p];
      ssq += live ? v*v : 0.0f;
    }
    ssq = wred64(ssq);
    float tj, scale;
    if (ssq == 0.0f){ tj = 0.0f; scale = 0.0f; }
    else {
      float bta = -copysignf(sqrtf(alpha*alpha + ssq), alpha);
      tj = (bta - alpha)/bta;
      scale = 1.0f/(alpha - bta);
    }
    tau[j] = tj;
    #pragma unroll
    for (int p = 0; p < 8; p++){
      int row = p*64 + l;
      float v = A[j][p]*scale;
      A[j][p] = (row < j) ? 0.0f : (row == j ? 1.0f : v);
    }
    float e[8];
    #pragma unroll
    for (int c = 0; c < 8; c++){
      float d = 0.0f;
      #pragma unroll
      for (int p = 0; p < 8; p++) d += A[c][p]*A[j][p];
      e[c] = (c > j) ? d : 0.0f;
    }
    float s = rs8(e, l);
    #pragma unroll
    for (int c = j+1; c < 8; c++){
      float d = __shfl(s, BRV3(c), 64)*tj;
      #pragma unroll
      for (int p = 0; p < 8; p++) A[c][p] -= d*A[j][p];
    }
  }
  #pragma unroll
  for (int c = 0; c < 8; c++)
    #pragma unroll
    for (int p = 0; p < 8; p++)
      Q[c][p] = (p == 0 && l == c) ? 1.0f : 0.0f;
  #pragma unroll
  for (int j = 7; j >= 0; j--){
    float e[8];
    #pragma unroll
    for (int c = 0; c < 8; c++){
      float d = 0.0f;
      #pragma unroll
      for (int p = 0; p < 8; p++) d += Q[c][p]*A[j][p];
      e[c] = d;
    }
    float s = rs8(e, l);
    #pragma unroll
    for (int c = 0; c < 8; c++){
      float d = __shfl(s, BRV3(c), 64)*tau[j];
      #pragma unroll
      for (int p = 0; p < 8; p++) Q[c][p] -= d*A[j][p];
    }
  }
  #pragma unroll
  for (int c = 0; c < 8; c++)
    #pragma unroll
    for (int p = 0; p < 8; p++)
      g_ws[OFF_U + c*512 + p*64 + l] = Q[c][p];   // U[c][d] = Q[d][c]
}

// ---------------- K2: v = (x . W_eff^T) * vm + den partials -------------------------
// Coalesced loads: lane owns d in {l*4..l*4+3} U {256+l*4..256+l*4+3}.
__global__ __launch_bounds__(256) void k2_proj(const float* __restrict__ x,
                                               const float* __restrict__ vmask){
  int tid = threadIdx.x;
  int l = tid & 63, wv = tid >> 6;
  int g = blockIdx.x*4 + wv;           // wave id 0..4095, 8 rows each
  __shared__ float denw[4];
  float u[8][8];
  #pragma unroll
  for (int k = 0; k < 8; k++){
    #pragma unroll
    for (int e = 0; e < 4; e++) u[k][e]   = g_ws[OFF_U + k*512 + l*4 + e];
    #pragma unroll
    for (int e = 0; e < 4; e++) u[k][4+e] = g_ws[OFF_U + k*512 + 256 + l*4 + e];
  }
  int kk = BRV3(l & 7);
  float pacc[8], psq[8];
  #pragma unroll
  for (int rr = 0; rr < 8; rr++){
    int row = g*8 + rr;
    const float* xr = x + (size_t)row*512;
    float4 xa = *(const float4*)(xr + l*4);
    float4 xb = *(const float4*)(xr + 256 + l*4);
    float xe[8] = {xa.x, xa.y, xa.z, xa.w, xb.x, xb.y, xb.z, xb.w};
    float acc[8];
    float sq = 0.0f;
    #pragma unroll
    for (int k = 0; k < 8; k++){
      float a = 0.0f;
      #pragma unroll
      for (int e = 0; e < 8; e++) a += xe[e]*u[k][e];
      acc[k] = a;
    }
    #pragma unroll
    for (int e = 0; e < 8; e++) sq += xe[e]*xe[e];
    if (l & 1){ float t;
      t=acc[0];acc[0]=acc[4];acc[4]=t; t=acc[1];acc[1]=acc[5];acc[5]=t;
      t=acc[2];acc[2]=acc[6];acc[6]=t; t=acc[3];acc[3]=acc[7];acc[7]=t; }
    acc[0] += __shfl_xor(acc[4], 1, 64);
    acc[1] += __shfl_xor(acc[5], 1, 64);
    acc[2] += __shfl_xor(acc[6], 1, 64);
    acc[3] += __shfl_xor(acc[7], 1, 64);
    if (l & 2){ float t;
      t=acc[0];acc[0]=acc[2];acc[2]=t; t=acc[1];acc[1]=acc[3];acc[3]=t; }
    acc[0] += __shfl_xor(acc[2], 2, 64);
    acc[1] += __shfl_xor(acc[3], 2, 64);
    if (l & 4){ float t=acc[0];acc[0]=acc[1];acc[1]=t; }
    acc[0] += __shfl_xor(acc[1], 4, 64);
    pacc[rr] = acc[0];                 // group-partial for k = kk
    psq[rr]  = sq;                     // lane-local partial for row rr
  }
  #pragma unroll
  for (int rr = 0; rr < 8; rr++){
    pacc[rr] += __shfl_xor(pacc[rr],  8, 64);
    pacc[rr] += __shfl_xor(pacc[rr], 16, 64);
    pacc[rr] += __shfl_xor(pacc[rr], 32, 64);
  }
  float dsq = sqrtf(rs8(psq, l));      // sqrt ||x_row||, row index kk
  dsq += __shfl_xor(dsq, 1, 64);
  dsq += __shfl_xor(dsq, 2, 64);
  dsq += __shfl_xor(dsq, 4, 64);       // sum over the 8 rows (kk bijective)
  float c0 = (l & 32) ? pacc[4] : pacc[0];
  float c1 = (l & 32) ? pacc[5] : pacc[1];
  float c2 = (l & 32) ? pacc[6] : pacc[2];
  float c3 = (l & 32) ? pacc[7] : pacc[3];
  float d0 = (l & 16) ? c2 : c0;
  float d1 = (l & 16) ? c3 : c1;
  float val = (l & 8) ? d1 : d0;
  int rowl = g*8 + (l >> 3);
  float vm = vmask[rowl];
  int b = rowl >> 14, t = (rowl >> 7) & 127, n = rowl & 127;
  int bn = b*128 + n;
  g_ws[OFF_V + bn*1024 + kk*128 + t] = val*vm;   // all 64 lanes store
  if (l == 0) denw[wv] = dsq;
  __syncthreads();
  if (tid == 0) g_ws[OFF_DENP + blockIdx.x] = denw[0]+denw[1]+denw[2]+denw[3];
}

// ---------------- K3: sort + isotonic soft-sort + quantiles + legendre coeffs -------
__global__ __launch_bounds__(256) void k3_sortfeat(){
  int tid = threadIdx.x;
  int l = tid & 63, wv = tid >> 6;
  int rho = blockIdx.x*4 + wv;         // 0..2047 = bn*8 + k
  __shared__ float orig[4][128], srt[4][128], Bl[384];
  __shared__ float pS[4][128];
  __shared__ int   pC[4][128];
  __shared__ float nrmS[2];
  if (tid < 128){
    float t = -1.0f + 2.0f*(float)tid/127.0f;
    Bl[128+tid] = t;
    Bl[256+tid] = 0.5f*(3.0f*t*t - 1.0f);
  }
  const float* vr = g_ws + OFF_V + rho*128;
  orig[wv][2*l]   = vr[2*l];
  orig[wv][2*l+1] = vr[2*l+1];
  srt[wv][2*l] = 0.0f; srt[wv][2*l+1] = 0.0f;
  __syncthreads();
  if (tid < 64){
    float a = Bl[128+tid]*Bl[128+tid] + Bl[192+tid]*Bl[192+tid];
    float b = Bl[256+tid]*Bl[256+tid] + Bl[320+tid]*Bl[320+tid];
    a = wred64(a); b = wred64(b);
    if (tid == 0){
      nrmS[0] = sqrtf(fmaxf(a, 1e-6f));
      nrmS[1] = sqrtf(fmaxf(b, 1e-6f));
    }
  }
  __syncthreads();
  if (tid < 128){
    Bl[tid] = 0.08838834764831845f;   // 1/sqrt(128)
    Bl[128+tid] /= nrmS[0];
    Bl[256+tid] /= nrmS[1];
  }
  __syncthreads();
  float c0, c1, c2;
  {
    float a = orig[wv][2*l], b = orig[wv][2*l+1];
    c0 = a*Bl[2*l]       + b*Bl[2*l+1];
    c1 = a*Bl[128+2*l]   + b*Bl[128+2*l+1];
    c2 = a*Bl[256+2*l]   + b*Bl[256+2*l+1];
  }
  c0 = wred64(c0); c1 = wred64(c1); c2 = wred64(c2);
  float e0 = orig[wv][2*l], e1 = orig[wv][2*l+1];
  int r0 = 0, r1 = 0;
  #pragma unroll 4
  for (int j = 0; j < 128; j++){
    float vj = orig[wv][j];
    r0 += (vj < e0) || (vj == e0 && j < 2*l);
    r1 += (vj < e1) || (vj == e1 && j < 2*l+1);
  }
  srt[wv][r0] = e0;
  srt[wv][r1] = e1;
  __syncthreads();
  const float rinv = 22.627416997969522f;  // 1/reg, reg = 0.5*128^-0.5
  bool v0 = (srt[wv][2*l+1] - srt[wv][2*l] > rinv);
  bool v1 = (2*l + 2 < 128) ? (srt[wv][2*l+2] - srt[wv][2*l+1] > rinv) : false;
  if (__any(v0 || v1)){
    if (l == 0){
      int top = -1;
      for (int i = 0; i < 128; i++){
        float y = (float)(128 - i)*rinv + srt[wv][i];
        top++; pS[wv][top] = y; pC[wv][top] = 1;
        while (top > 0 &&
               pS[wv][top]*(float)pC[wv][top-1] > pS[wv][top-1]*(float)pC[wv][top]){
          pS[wv][top-1] += pS[wv][top];
          pC[wv][top-1] += pC[wv][top];
          top--;
        }
      }
      int i = 0;
      for (int blk = 0; blk <= top; blk++){
        float m = pS[wv][blk]/(float)pC[wv][blk];
        for (int c = 0; c < pC[wv][blk]; c++){
          srt[wv][i] = m - (float)(128 - i)*rinv;
          i++;
        }
      }
    }
  }
  if (l == 0){
    int bn = rho >> 3, k = rho & 7;
    float* fb = g_ws + OFF_FEATS + bn*48 + k*6;
    float w0 = 0.1f*127.0f - 12.0f;
    float w1 = 0.5f*127.0f - 63.0f;
    float w2 = 0.9f*127.0f - 114.0f;
    fb[0] = (1.0f - w0)*srt[wv][12]  + w0*srt[wv][13];
    fb[1] = (1.0f - w1)*srt[wv][63]  + w1*srt[wv][64];
    fb[2] = (1.0f - w2)*srt[wv][114] + w2*srt[wv][115];
    fb[3] = c0; fb[4] = c1; fb[5] = c2;
  }
}

// ---------------- K4a: head partials. Block = (bn-pair, f-slice of 6) ---------------
__global__ __launch_bounds__(512) void k4a_head(const float* __restrict__ W1,
                                                const float* __restrict__ b1,
                                                const float* __restrict__ W2,
                                                const float* __restrict__ beta){
  int blk = blockIdx.x;                 // 0..1023
  int s   = blk & 7;                    // f-slice: f in [s*6, s*6+6)
  int bnp = blk >> 3;                   // 0..127
  int bn0 = bnp*2, bn1 = bn0 + 1;
  int tid = threadIdx.x;                // = d
  int l = tid & 63, wv = tid >> 6;      // 8 waves
  __shared__ float hl0[96], hl1[96];
  __shared__ float sq[8][12];
  if (tid < 192){
    int which = tid >= 96;
    int i = which ? tid - 96 : tid;     // f_local*16 + w
    int f = s*6 + (i >> 4);
    int k = f*16 + (i & 15);
    int bn = which ? bn1 : bn0;
    float a = g_ws[OFF_FEATS + bn*48 + f]*W1[k] + b1[k];
    float g = 0.5f*a*(1.0f + erff(a*0.70710678118654752f));  // exact GELU
    if (which) hl1[i] = g; else hl0[i] = g;
  }
  __syncthreads();
  int d = tid;
  float be = 1.0f/(1.0f + expf(-beta[d]));
  float b2 = be*be;
  float y0 = 0.0f, y1 = 0.0f;
  float ev[12];
  const float* w2base = W2 + (size_t)(s*96)*512 + d;
  #pragma unroll
  for (int fl_ = 0; fl_ < 6; fl_++){
    float p0 = 0.0f, p1 = 0.0f;
    #pragma unroll
    for (int w = 0; w < 16; w++){
      float w2 = w2base[(size_t)(fl_*16 + w)*512];
      p0 += hl0[fl_*16 + w]*w2;
      p1 += hl1[fl_*16 + w]*w2;
    }
    y0 += p0; y1 += p1;
    ev[fl_*2]     = p0*p0*b2;
    ev[fl_*2 + 1] = p1*p1*b2;
  }
  g_ws[OFF_YP + (size_t)(bn0*8 + s)*512 + d] = y0;
  g_ws[OFF_YP + (size_t)(bn1*8 + s)*512 + d] = y1;
  int kk = BRV3(l & 7);
  {
    float e8[8] = {ev[0],ev[1],ev[2],ev[3],ev[4],ev[5],ev[6],ev[7]};
    float a0 = rs8(e8, l);
    if (l < 8) sq[wv][kk] = a0;
  }
  {
    float e8[8] = {ev[8],ev[9],ev[10],ev[11],0,0,0,0};
    float a0 = rs8(e8, l);
    if (l < 8 && kk < 4) sq[wv][8 + kk] = a0;
  }
  __syncthreads();
  if (tid < 12){
    float t = 0.0f;
    #pragma unroll
    for (int w = 0; w < 8; w++) t += sq[w][tid];
    int fl_ = tid >> 1, which = tid & 1;
    int bn = which ? bn1 : bn0;
    g_ws[OFF_SQP + bn*48 + s*6 + fl_] = t;
  }
}

// ---------------- K4b: y = sum of slice partials; num per bn ------------------------
__global__ __launch_bounds__(512) void k4b_red(const float* __restrict__ beta){
  int bn = blockIdx.x;
  int tid = threadIdx.x;
  int l = tid & 63, wv = tid >> 6;
  __shared__ float nw[8];
  float y = 0.0f;
  #pragma unroll
  for (int s = 0; s < 8; s++) y += g_ws[OFF_YP + (size_t)(bn*8 + s)*512 + tid];
  g_ws[OFF_Y + bn*512 + tid] = y;
  float be = 1.0f/(1.0f + expf(-beta[tid]));
  float by = be*y;
  float ns = wred64(by*by);
  if (l == 0) nw[wv] = ns;
  __syncthreads();
  if (tid == 0){
    float s = nw[0]+nw[1]+nw[2]+nw[3]+nw[4]+nw[5]+nw[6]+nw[7];
    g_ws[OFF_NUMP + bn] = sqrtf(s);
  }
}

// ---------------- K7: h epilogue (2 quads/thread); block 8192 finalizes r/r_feat ----
__global__ __launch_bounds__(256) void k7_out(const float* __restrict__ x,
                                              const float* __restrict__ vmask,
                                              const float* __restrict__ beta,
                                              float* __restrict__ outt){
  if (blockIdx.x == 8192){
    __shared__ float red[256];
    __shared__ float en[96];
    __shared__ float scal[2];
    int tid = threadIdx.x;
    float dp = 0.0f;
    for (int i = tid; i < 1024; i += 256) dp += g_ws[OFF_DENP + i];
    red[tid] = dp; __syncthreads();
    for (int s = 128; s > 0; s >>= 1){
      if (tid < s) red[tid] += red[tid + s];
      __syncthreads();
    }
    if (tid == 0) scal[0] = fmaxf(red[0]/32768.0f, 1e-9f);
    __syncthreads();
    red[tid] = g_ws[OFF_NUMP + tid];
    __syncthreads();
    for (int s = 128; s > 0; s >>= 1){
      if (tid < s) red[tid] += red[tid + s];
      __syncthreads();
    }
    if (tid == 0) scal[1] = red[0]/256.0f;
    __syncthreads();
    float den = scal[0];
    if (tid < 96){
      int b = tid/48, f = tid%48;
      float s = 0.0f;
      for (int j = 0; j < 128; j++) s += g_ws[OFF_SQP + (b*128 + j)*48 + f];
      en[tid] = sqrtf(128.0f*s);
    }
    __syncthreads();
    if (tid == 0) outt[16777216] = scal[1]/den;
    if (tid < 48) outt[16777217 + tid] = 0.5f*(en[tid] + en[48 + tid])/den;
    return;
  }
  #pragma unroll
  for (int it = 0; it < 2; it++){
    int q = blockIdx.x*256 + threadIdx.x + it*2097152;  // quad id < 4194304
    size_t fl = (size_t)q*4;
    int d = (int)(fl & 511);
    int row = (int)(fl >> 9);
    int b = row >> 14, n = row & 127;
    int bn = b*128 + n;
    float vm = vmask[row];
    float4 xv = *(const float4*)(x + fl);
    float4 yv = *(const float4*)(g_ws + OFF_Y + bn*512 + d);
    float4 bt = *(const float4*)(beta + d);
    float4 bv;
    bv.x = 1.0f/(1.0f + expf(-bt.x));
    bv.y = 1.0f/(1.0f + expf(-bt.y));
    bv.z = 1.0f/(1.0f + expf(-bt.z));
    bv.w = 1.0f/(1.0f + expf(-bt.w));
    float4 o;
    o.x = xv.x + vm*bv.x*yv.x;
    o.y = xv.y + vm*bv.y*yv.y;
    o.z = xv.z + vm*bv.z*yv.z;
    o.w = xv.w + vm*bv.w*yv.w;
    *(float4*)(outt + fl) = o;
  }
}

extern "C" void kernel_launch(void* const* d_in, const int* in_sizes, int n_in,
                              void* d_out, int out_size, void* d_ws, size_t ws_size,
                              hipStream_t stream){
  (void)out_size; (void)d_ws; (void)ws_size;
  const float *x=nullptr,*vm=nullptr,*Wp=nullptr,*W1=nullptr,*b1=nullptr,*W2=nullptr,*beta=nullptr;
  for (int i = 0; i < n_in; i++){
    int s = in_sizes[i];
    const float* p = (const float*)d_in[i];
    if      (s == 16777216) x = p;
    else if (s == 32768)    vm = p;
    else if (s == 4096)     Wp = p;
    else if (s == 393216)   W2 = p;
    else if (s == 512)      beta = p;
    else if (s == 768)      { if (!W1) W1 = p; else b1 = p; }
  }
  float* out = (float*)d_out;

  k1_prep<<<1, 64, 0, stream>>>(Wp);
  k2_proj<<<1024, 256, 0, stream>>>(x, vm);
  k3_sortfeat<<<512, 256, 0, stream>>>();
  k4a_head<<<1024, 512, 0, stream>>>(W1, b1, W2, beta);
  k4b_red<<<256, 512, 0, stream>>>(beta);
  k7_out<<<8193, 256, 0, stream>>>(x, vm, beta, out);
}